// Round 1
// baseline (234.498 us; speedup 1.0000x reference)
//
#include <hip/hip_runtime.h>
#include <math.h>

#define Bb 2
#define Ss 128
#define Hh 768
#define Cc 5
#define NT 4608      // Hh + Cc*Hh
#define Mm 256       // Bb*Ss
#define NEGV -1024.0f

__device__ __forceinline__ float tanh_fast(float x) {
    x = fminf(15.0f, fmaxf(-15.0f, x));
    float e = __builtin_amdgcn_exp2f(x * 2.8853900817779268f);   // e^(2x)
    return (e - 1.0f) * __builtin_amdgcn_rcpf(e + 1.0f);
}

// ---------------- Kernel 1: Hall[m][n] = X[m][:] . Wcat[n][:] + bias[n] ----------------
// Wcat = [W_prd (768 rows); W_arg (3840 rows)], all rows K=768 contiguous.
#define BM 64
#define BN 64
#define BK 16

__global__ __launch_bounds__(256)
void gemm_hall(const float* __restrict__ X,
               const float* __restrict__ Wprd,
               const float* __restrict__ Warg,
               const float* __restrict__ bprd,
               const float* __restrict__ barg,
               float* __restrict__ Hall)
{
    __shared__ float As[BK][BM + 4];
    __shared__ float Bs[BK][BN + 4];
    const int bm = blockIdx.x;   // 0..3
    const int bn = blockIdx.y;   // 0..71
    const int tid = threadIdx.x;

    const float* Wsrc;
    const float* bsrc;
    if (bn < 12) { Wsrc = Wprd + (size_t)bn * 64 * Hh;        bsrc = bprd + bn * 64; }
    else         { Wsrc = Warg + (size_t)(bn - 12) * 64 * Hh; bsrc = barg + (bn - 12) * 64; }

    const int lr = tid >> 2;          // 0..63: tile row to load
    const int lk = (tid & 3) * 4;     // 0,4,8,12: k sub-offset

    const int tx = tid & 15;
    const int ty = tid >> 4;
    const int mb = ty * 4;
    const int nb = tx * 4;

    float acc[4][4] = {};

    for (int k0 = 0; k0 < Hh; k0 += BK) {
        float4 av = *(const float4*)(X    + (size_t)(bm * 64 + lr) * Hh + k0 + lk);
        float4 bv = *(const float4*)(Wsrc + (size_t)lr * Hh + k0 + lk);
        As[lk + 0][lr] = av.x; As[lk + 1][lr] = av.y; As[lk + 2][lr] = av.z; As[lk + 3][lr] = av.w;
        Bs[lk + 0][lr] = bv.x; Bs[lk + 1][lr] = bv.y; Bs[lk + 2][lr] = bv.z; Bs[lk + 3][lr] = bv.w;
        __syncthreads();
        #pragma unroll
        for (int k = 0; k < BK; ++k) {
            float4 a4 = *(const float4*)&As[k][mb];
            float4 b4 = *(const float4*)&Bs[k][nb];
            acc[0][0] += a4.x * b4.x; acc[0][1] += a4.x * b4.y; acc[0][2] += a4.x * b4.z; acc[0][3] += a4.x * b4.w;
            acc[1][0] += a4.y * b4.x; acc[1][1] += a4.y * b4.y; acc[1][2] += a4.y * b4.z; acc[1][3] += a4.y * b4.w;
            acc[2][0] += a4.z * b4.x; acc[2][1] += a4.z * b4.y; acc[2][2] += a4.z * b4.z; acc[2][3] += a4.z * b4.w;
            acc[3][0] += a4.w * b4.x; acc[3][1] += a4.w * b4.y; acc[3][2] += a4.w * b4.z; acc[3][3] += a4.w * b4.w;
        }
        __syncthreads();
    }

    float4 bias = *(const float4*)(bsrc + nb);
    #pragma unroll
    for (int i = 0; i < 4; ++i) {
        float4 o;
        o.x = acc[i][0] + bias.x;
        o.y = acc[i][1] + bias.y;
        o.z = acc[i][2] + bias.z;
        o.w = acc[i][3] + bias.w;
        *(float4*)(Hall + (size_t)(bm * 64 + mb + i) * NT + bn * 64 + nb) = o;
    }
}

// ---------------- Kernel 2: biaffine + mask + logits + log-softmax + loss ----------------
// One block per (b,p); 640 threads = one per (c,a).
__global__ __launch_bounds__(640)
void biaffine_loss(const float* __restrict__ Hall,
                   const float* __restrict__ Wout,
                   const int* __restrict__ ng,      // bool mask delivered as int32
                   const int* __restrict__ att,
                   const float* __restrict__ target,
                   float* __restrict__ out_logits,  // d_out + 1
                   float* __restrict__ accum)       // {num, den}
{
    __shared__ float hp_s[Hh];
    __shared__ float wout_s[Cc * Hh];
    __shared__ float maskneg[Ss];
    __shared__ float redmax[Cc][2];
    __shared__ float red3[Cc][2][3];

    const int bp = blockIdx.x;      // b*128 + p
    const int b  = bp >> 7;
    const int tid = threadIdx.x;

    for (int i = tid; i < Hh; i += 640)      hp_s[i]  = Hall[(size_t)bp * NT + i];
    for (int i = tid; i < Cc * Hh; i += 640) wout_s[i] = Wout[i];
    if (tid < Ss) {
        const int a = tid;
        int any = 0;
        if (att[b * Ss + a] > 0) {
            const int* ngp = ng + (size_t)bp * Cc * Ss + a;
            #pragma unroll
            for (int c = 0; c < Cc; ++c) any |= ngp[c * Ss];
        }
        maskneg[a] = any ? 0.0f : NEGV;
    }
    __syncthreads();

    const int c = tid >> 7;          // 0..4
    const int a = tid & (Ss - 1);    // 0..127
    const float* hap = Hall + (size_t)(b * Ss + a) * NT + Hh + c * Hh;
    const float* wc  = wout_s + c * Hh;

    float ac0 = 0.f, ac1 = 0.f, ac2 = 0.f, ac3 = 0.f;
    for (int h = 0; h < Hh; h += 8) {
        float4 g0 = *(const float4*)(hap + h);
        float4 g1 = *(const float4*)(hap + h + 4);
        float4 p0 = *(const float4*)(hp_s + h);
        float4 p1 = *(const float4*)(hp_s + h + 4);
        float4 w0 = *(const float4*)(wc + h);
        float4 w1 = *(const float4*)(wc + h + 4);
        ac0 += tanh_fast(p0.x + g0.x) * w0.x;
        ac1 += tanh_fast(p0.y + g0.y) * w0.y;
        ac2 += tanh_fast(p0.z + g0.z) * w0.z;
        ac3 += tanh_fast(p0.w + g0.w) * w0.w;
        ac0 += tanh_fast(p1.x + g1.x) * w1.x;
        ac1 += tanh_fast(p1.y + g1.y) * w1.y;
        ac2 += tanh_fast(p1.z + g1.z) * w1.z;
        ac3 += tanh_fast(p1.w + g1.w) * w1.w;
    }
    const float logit = (ac0 + ac1) + (ac2 + ac3) + maskneg[a];
    out_logits[((size_t)bp * Cc + c) * Ss + a] = logit;

    // ---- log-softmax over a (row = (bp,c): 128 entries = 2 waves) + loss terms ----
    const int lane = tid & 63;
    const int half = a >> 6;
    float mx = logit;
    #pragma unroll
    for (int off = 32; off > 0; off >>= 1)
        mx = fmaxf(mx, __shfl_xor(mx, off, 64));
    if (lane == 0) redmax[c][half] = mx;
    __syncthreads();
    const float rm = fmaxf(redmax[c][0], redmax[c][1]);

    const float e  = __builtin_amdgcn_exp2f((logit - rm) * 1.4426950408889634f);
    const float tg = target[((size_t)bp * Cc + c) * Ss + a];
    float se = e, st = tg, sx = tg * logit;
    #pragma unroll
    for (int off = 32; off > 0; off >>= 1) {
        se += __shfl_xor(se, off, 64);
        st += __shfl_xor(st, off, 64);
        sx += __shfl_xor(sx, off, 64);
    }
    if (lane == 0) { red3[c][half][0] = se; red3[c][half][1] = st; red3[c][half][2] = sx; }
    __syncthreads();
    if (a == 0) {
        const float SE = red3[c][0][0] + red3[c][1][0];
        const float ST = red3[c][0][1] + red3[c][1][1];
        const float SX = red3[c][0][2] + red3[c][1][2];
        const float lse = rm + __builtin_amdgcn_logf(SE) * 0.6931471805599453f;
        atomicAdd(&accum[0], lse * ST - SX);   // sum target*(lse - x)
        atomicAdd(&accum[1], ST);              // sum target
    }
}

__global__ void finalize_loss(const float* __restrict__ accum, float* __restrict__ out)
{
    out[0] = accum[0] / accum[1];
}

extern "C" void kernel_launch(void* const* d_in, const int* in_sizes, int n_in,
                              void* d_out, int out_size, void* d_ws, size_t ws_size,
                              hipStream_t stream) {
    const float* seq    = (const float*)d_in[0];
    const int*   att    = (const int*)  d_in[1];
    const int*   ng     = (const int*)  d_in[2];
    const float* target = (const float*)d_in[3];
    const float* Wprd   = (const float*)d_in[4];
    const float* bprd   = (const float*)d_in[5];
    const float* Warg   = (const float*)d_in[6];
    const float* barg   = (const float*)d_in[7];
    const float* Wout   = (const float*)d_in[8];

    float* out   = (float*)d_out;
    float* Hall  = (float*)d_ws;                     // 256 x 4608 fp32
    float* accum = Hall + (size_t)Mm * NT;           // 2 floats

    hipMemsetAsync(accum, 0, 2 * sizeof(float), stream);
    gemm_hall<<<dim3(4, 72), 256, 0, stream>>>(seq, Wprd, Warg, bprd, barg, Hall);
    biaffine_loss<<<dim3(Mm), 640, 0, stream>>>(Hall, Wout, ng, att, target, out + 1, accum);
    finalize_loss<<<1, 1, 0, stream>>>(accum, out);
}

// Round 2
// 220.916 us; speedup vs baseline: 1.0615x; 1.0615x over previous
//
#include <hip/hip_runtime.h>
#include <math.h>

#define Bb 2
#define Ss 128
#define Hh 768
#define Cc 5
#define NT 4608      // Hh + Cc*Hh
#define Mm 256       // Bb*Ss
#define NEGV -1024.0f
#define SCALE 2.8853900817779268f   // 2/ln(2): Hall pre-scaled so exp2(hp'+ha') = e^{2x}

typedef __attribute__((ext_vector_type(8))) short bf16x8;
typedef __attribute__((ext_vector_type(4))) float f32x4;

// ---------------- Kernel 1: bf16 MFMA GEMM  Hall = SCALE*(X.Wcat^T + bias) ----------------
// Block: 256 thr = 4 waves. Tile: M=64 (wave m-strips of 16) x N=32 (2 MFMA n-tiles).
// Grid (4, 144). A and W are K-major (row-major with K contiguous) -> both frags load identically.
__device__ __forceinline__ unsigned pack_hi16(float hi, float lo) {
    // [bf16(hi) : bf16(lo)] by truncation
    return (__float_as_uint(hi) & 0xFFFF0000u) | (__float_as_uint(lo) >> 16);
}

__device__ __forceinline__ bf16x8 pack_bf16x8(float4 lo, float4 hi) {
    union { bf16x8 v; unsigned u[4]; } r;
    r.u[0] = pack_hi16(lo.y, lo.x);
    r.u[1] = pack_hi16(lo.w, lo.z);
    r.u[2] = pack_hi16(hi.y, hi.x);
    r.u[3] = pack_hi16(hi.w, hi.z);
    return r.v;
}

__global__ __launch_bounds__(256)
void gemm_mfma(const float* __restrict__ X,
               const float* __restrict__ Wprd,
               const float* __restrict__ Warg,
               const float* __restrict__ bprd,
               const float* __restrict__ barg,
               float* __restrict__ Hall)
{
    const int bm   = blockIdx.x;          // 0..3   (64 rows)
    const int bn   = blockIdx.y;          // 0..143 (32 cols)
    const int wave = threadIdx.x >> 6;    // 0..3
    const int lane = threadIdx.x & 63;
    const int l16  = lane & 15;
    const int quad = lane >> 4;

    const float* Wsrc; const float* bsrc;
    const int nb = bn * 32;
    if (nb < Hh) { Wsrc = Wprd + (size_t)nb * Hh;        bsrc = bprd + nb; }
    else         { Wsrc = Warg + (size_t)(nb - Hh) * Hh; bsrc = barg + (nb - Hh); }

    const int m_g = bm * 64 + wave * 16 + l16;
    const float* arow  = X    + (size_t)m_g * Hh + quad * 8;
    const float* brow0 = Wsrc + (size_t)l16 * Hh + quad * 8;
    const float* brow1 = Wsrc + (size_t)(16 + l16) * Hh + quad * 8;

    f32x4 acc0 = {0.f, 0.f, 0.f, 0.f};
    f32x4 acc1 = {0.f, 0.f, 0.f, 0.f};

    #pragma unroll 2
    for (int k = 0; k < Hh; k += 32) {
        float4 a0  = *(const float4*)(arow  + k);
        float4 a1  = *(const float4*)(arow  + k + 4);
        float4 b00 = *(const float4*)(brow0 + k);
        float4 b01 = *(const float4*)(brow0 + k + 4);
        float4 b10 = *(const float4*)(brow1 + k);
        float4 b11 = *(const float4*)(brow1 + k + 4);
        bf16x8 af  = pack_bf16x8(a0,  a1);
        bf16x8 bf0 = pack_bf16x8(b00, b01);
        bf16x8 bf1 = pack_bf16x8(b10, b11);
        acc0 = __builtin_amdgcn_mfma_f32_16x16x32_bf16(af, bf0, acc0, 0, 0, 0);
        acc1 = __builtin_amdgcn_mfma_f32_16x16x32_bf16(af, bf1, acc1, 0, 0, 0);
    }

    // epilogue: D element (m = quad*4 + r, n = lane&15); Hall = S*acc + S*bias
    const float sb0 = SCALE * bsrc[l16];
    const float sb1 = SCALE * bsrc[16 + l16];
    const int row = bm * 64 + wave * 16 + quad * 4;
    const int col0 = nb + l16;
    const int col1 = nb + 16 + l16;
    #pragma unroll
    for (int r = 0; r < 4; ++r) {
        Hall[(size_t)(row + r) * NT + col0] = SCALE * acc0[r] + sb0;
        Hall[(size_t)(row + r) * NT + col1] = SCALE * acc1[r] + sb1;
    }
}

// ---------------- Kernel 2: biaffine + mask + logits + log-softmax + loss ----------------
// One block per (b,p); 640 threads = one per (c,a). Hall is pre-scaled by 2/ln2.
// tanh(x) = 1 - 2/(e^{2x}+1) = fma(-2, rcp(exp2(t)+1), 1) with t = hp'+ha'.
__device__ __forceinline__ void tanh_dot4(float4 g, const float* __restrict__ hp,
                                          const float* __restrict__ w,
                                          float& a0, float& a1, float& a2, float& a3)
{
    float4 p  = *(const float4*)hp;
    float4 wv = *(const float4*)w;
    float e0 = __builtin_amdgcn_exp2f(p.x + g.x);
    float e1 = __builtin_amdgcn_exp2f(p.y + g.y);
    float e2 = __builtin_amdgcn_exp2f(p.z + g.z);
    float e3 = __builtin_amdgcn_exp2f(p.w + g.w);
    float r0 = __builtin_amdgcn_rcpf(e0 + 1.0f);
    float r1 = __builtin_amdgcn_rcpf(e1 + 1.0f);
    float r2 = __builtin_amdgcn_rcpf(e2 + 1.0f);
    float r3 = __builtin_amdgcn_rcpf(e3 + 1.0f);
    a0 = fmaf(wv.x, fmaf(-2.0f, r0, 1.0f), a0);
    a1 = fmaf(wv.y, fmaf(-2.0f, r1, 1.0f), a1);
    a2 = fmaf(wv.z, fmaf(-2.0f, r2, 1.0f), a2);
    a3 = fmaf(wv.w, fmaf(-2.0f, r3, 1.0f), a3);
}

__global__ __launch_bounds__(640)
void biaffine_loss(const float* __restrict__ Hall,
                   const float* __restrict__ Wout,
                   const int* __restrict__ ng,
                   const int* __restrict__ att,
                   const float* __restrict__ target,
                   float* __restrict__ out_logits,  // d_out + 1
                   float* __restrict__ accum)       // {num, den}
{
    __shared__ float hp_s[Hh];
    __shared__ float wout_s[Cc * Hh];
    __shared__ float maskneg[Ss];
    __shared__ float redmax[Cc][2];
    __shared__ float red3[Cc][2][3];

    const int bp = blockIdx.x;      // b*128 + p
    const int b  = bp >> 7;
    const int tid = threadIdx.x;

    for (int i = tid; i < Hh; i += 640)      hp_s[i]   = Hall[(size_t)bp * NT + i];
    for (int i = tid; i < Cc * Hh; i += 640) wout_s[i] = Wout[i];
    if (tid < Ss) {
        const int a = tid;
        int any = 0;
        if (att[b * Ss + a] > 0) {
            const int* ngp = ng + (size_t)bp * Cc * Ss + a;
            #pragma unroll
            for (int c = 0; c < Cc; ++c) any |= ngp[c * Ss];
        }
        maskneg[a] = any ? 0.0f : NEGV;
    }
    __syncthreads();

    const int c = tid >> 7;          // 0..4
    const int a = tid & (Ss - 1);    // 0..127
    const float* hap = Hall + (size_t)(b * Ss + a) * NT + Hh + c * Hh;
    const float* wc  = wout_s + c * Hh;

    float ac0 = 0.f, ac1 = 0.f, ac2 = 0.f, ac3 = 0.f;
    float4 g0 = *(const float4*)(hap);
    float4 g1 = *(const float4*)(hap + 4);
    float4 g2 = *(const float4*)(hap + 8);
    float4 g3 = *(const float4*)(hap + 12);
    for (int h = 0; h < Hh; h += 16) {
        // prefetch next 64B (overruns <=64B past the last slice; d_ws pad covers it)
        float4 m0 = *(const float4*)(hap + h + 16);
        float4 m1 = *(const float4*)(hap + h + 20);
        float4 m2 = *(const float4*)(hap + h + 24);
        float4 m3 = *(const float4*)(hap + h + 28);
        tanh_dot4(g0, hp_s + h,      wc + h,      ac0, ac1, ac2, ac3);
        tanh_dot4(g1, hp_s + h + 4,  wc + h + 4,  ac0, ac1, ac2, ac3);
        tanh_dot4(g2, hp_s + h + 8,  wc + h + 8,  ac0, ac1, ac2, ac3);
        tanh_dot4(g3, hp_s + h + 12, wc + h + 12, ac0, ac1, ac2, ac3);
        g0 = m0; g1 = m1; g2 = m2; g3 = m3;
    }
    const float logit = (ac0 + ac1) + (ac2 + ac3) + maskneg[a];
    out_logits[((size_t)bp * Cc + c) * Ss + a] = logit;

    // ---- log-softmax over a (row = (bp,c): 128 entries = 2 waves) + loss terms ----
    const int lane = tid & 63;
    const int half = a >> 6;
    float mx = logit;
    #pragma unroll
    for (int off = 32; off > 0; off >>= 1)
        mx = fmaxf(mx, __shfl_xor(mx, off, 64));
    if (lane == 0) redmax[c][half] = mx;
    __syncthreads();
    const float rm = fmaxf(redmax[c][0], redmax[c][1]);

    const float e  = __builtin_amdgcn_exp2f((logit - rm) * 1.4426950408889634f);
    const float tg = target[((size_t)bp * Cc + c) * Ss + a];
    float se = e, st = tg, sx = tg * logit;
    #pragma unroll
    for (int off = 32; off > 0; off >>= 1) {
        se += __shfl_xor(se, off, 64);
        st += __shfl_xor(st, off, 64);
        sx += __shfl_xor(sx, off, 64);
    }
    if (lane == 0) { red3[c][half][0] = se; red3[c][half][1] = st; red3[c][half][2] = sx; }
    __syncthreads();
    if (a == 0) {
        const float SE = red3[c][0][0] + red3[c][1][0];
        const float ST = red3[c][0][1] + red3[c][1][1];
        const float SX = red3[c][0][2] + red3[c][1][2];
        const float lse = rm + __builtin_amdgcn_logf(SE) * 0.6931471805599453f;
        atomicAdd(&accum[0], lse * ST - SX);   // sum target*(lse - x)
        atomicAdd(&accum[1], ST);              // sum target
    }
}

__global__ void finalize_loss(const float* __restrict__ accum, float* __restrict__ out)
{
    out[0] = accum[0] / accum[1];
}

extern "C" void kernel_launch(void* const* d_in, const int* in_sizes, int n_in,
                              void* d_out, int out_size, void* d_ws, size_t ws_size,
                              hipStream_t stream) {
    const float* seq    = (const float*)d_in[0];
    const int*   att    = (const int*)  d_in[1];
    const int*   ng     = (const int*)  d_in[2];
    const float* target = (const float*)d_in[3];
    const float* Wprd   = (const float*)d_in[4];
    const float* bprd   = (const float*)d_in[5];
    const float* Warg   = (const float*)d_in[6];
    const float* barg   = (const float*)d_in[7];
    const float* Wout   = (const float*)d_in[8];

    float* out   = (float*)d_out;
    float* Hall  = (float*)d_ws;                     // 256 x 4608 fp32 (pre-scaled by 2/ln2)
    float* accum = Hall + (size_t)Mm * NT + 64;      // 256B pad covers prefetch overrun

    hipMemsetAsync(accum, 0, 2 * sizeof(float), stream);
    gemm_mfma<<<dim3(4, 144), 256, 0, stream>>>(seq, Wprd, Warg, bprd, barg, Hall);
    biaffine_loss<<<dim3(Mm), 640, 0, stream>>>(Hall, Wout, ng, att, target, out + 1, accum);
    finalize_loss<<<1, 1, 0, stream>>>(accum, out);
}